// Round 20
// baseline (132.532 us; speedup 1.0000x reference)
//
#include <hip/hip_runtime.h>

#define DIN 1024
#define LSEQ 2048

typedef _Float16 f16;
typedef _Float16 half8 __attribute__((ext_vector_type(8)));
typedef float floatx4 __attribute__((ext_vector_type(4)));

__device__ __forceinline__ void async_ld16(const void* g, void* l) {
  __builtin_amdgcn_global_load_lds(
      (const __attribute__((address_space(1))) void*)g,
      (__attribute__((address_space(3))) void*)l, 16, 0, 0);
}

__device__ __forceinline__ float fast_exp2(float x) {
#if __has_builtin(__builtin_amdgcn_exp2f)
  return __builtin_amdgcn_exp2f(x);
#else
  return exp2f(x);
#endif
}

__device__ __forceinline__ unsigned int pack2_f16(float a, float b) {
#if __has_builtin(__builtin_amdgcn_cvt_pkrtz)
  typedef __fp16 fp16x2 __attribute__((ext_vector_type(2)));
  fp16x2 h = __builtin_amdgcn_cvt_pkrtz(a, b);
  return __builtin_bit_cast(unsigned int, h);
#else
  union { f16 h[2]; unsigned int u; } pk;
  pk.h[0] = (f16)a; pk.h[1] = (f16)b;
  return pk.u;
#endif
}

// ------- Kernel 1: fused prep. z<3: W [k][n] fp32 -> Wt [n][k] f16;
//                   z=3,4: X fp32 -> f16 elementwise cast. -----------------
__global__ void __launch_bounds__(256) kprep(const float* __restrict__ xq,
                                             const float* __restrict__ xk,
                                             const float* __restrict__ wq,
                                             const float* __restrict__ wk,
                                             const float* __restrict__ wv,
                                             f16* __restrict__ wqt,
                                             f16* __restrict__ wkt,
                                             f16* __restrict__ wvt,
                                             f16* __restrict__ xqh,
                                             f16* __restrict__ xkh) {
  int z = blockIdx.z;
  int tid = threadIdx.x;
  if (z < 3) {
    __shared__ float t[32][33];
    const float* src = z == 0 ? wq : (z == 1 ? wk : wv);
    f16* dst = z == 0 ? wqt : (z == 1 ? wkt : wvt);
    int k0 = blockIdx.x * 32, n0 = blockIdx.y * 32;
    int tx = tid & 31, ty = tid >> 5;  // 32 x 8
#pragma unroll
    for (int r = 0; r < 4; ++r)
      t[ty + r * 8][tx] = src[(k0 + ty + r * 8) * DIN + n0 + tx];
    __syncthreads();
#pragma unroll
    for (int r = 0; r < 4; ++r)
      dst[(n0 + ty + r * 8) * DIN + k0 + tx] = (f16)t[tx][ty + r * 8];
  } else {
    const float4* src = (const float4*)(z == 4 ? xk : xq);
    uint2* dst = (uint2*)(z == 4 ? xkh : xqh);
    int bx = blockIdx.y * 32 + blockIdx.x;  // 0..1023
    int i = bx * 256 + tid;
#pragma unroll
    for (int it = 0; it < 4; ++it, i += 262144) {
      float4 v = src[i];
      union { unsigned int u[2]; uint2 w; } pk;
      pk.u[0] = pack2_f16(v.x, v.y);
      pk.u[1] = pack2_f16(v.z, v.w);
      dst[i] = pk.w;
    }
  }
}

// ------------- Kernel 2: C = X(4096x1024) @ W -> Q/K fp16, V^T fp16 --------
// (R17 grid/layout — the XCD remap of R19 was neutral and is reverted.)
template <int AMODE>
__global__ void __launch_bounds__(256) kproj(const float* __restrict__ xq,
                                             const float* __restrict__ xk,
                                             const f16* __restrict__ xqh,
                                             const f16* __restrict__ xkh,
                                             const f16* __restrict__ wqt,
                                             const f16* __restrict__ wkt,
                                             const f16* __restrict__ wvt,
                                             f16* __restrict__ qb,
                                             f16* __restrict__ kb,
                                             f16* __restrict__ vtb) {
  __shared__ __align__(16) char smem[34816];  // As 16K | Bs 16K ; z=2 epilogue
  char* As = smem;
  char* Bs = smem + 16384;
  const float* X;
  const f16* Xh;
  const f16* W;
  int z = blockIdx.z;
  if (z == 0) { X = xq; Xh = xqh; W = wqt; }
  else if (z == 1) { X = xk; Xh = xkh; W = wkt; }
  else { X = xk; Xh = xkh; W = wvt; }
  float oscale = (z == 0) ? 0.18033688011112042f : 1.0f;  // SC only for Q
  int m0 = blockIdx.y * 128, n0 = blockIdx.x * 128;
  int tid = threadIdx.x, lane = tid & 63, wid = tid >> 6;
  int wm = wid >> 1, wn = wid & 1;
  int c15 = lane & 15, g = lane >> 4;
  int l8 = lane >> 3, l7 = lane & 7;
  int kk = 8 * (l7 ^ l8);
  int swz = (c15 & 7) << 4;
  floatx4 acc[4][4] = {};

  for (int kt = 0; kt < 16; ++kt) {
    int k0 = kt * 64;
    if constexpr (AMODE == 1) {
#pragma unroll
      for (int cc = 0; cc < 4; ++cc) {
        int c = wid * 4 + cc;
        async_ld16(&Xh[(m0 + c * 8 + l8) * DIN + k0 + kk], As + c * 1024);
        async_ld16(&W[(n0 + c * 8 + l8) * DIN + k0 + kk], Bs + c * 1024);
      }
    } else {
#pragma unroll
      for (int cc = 0; cc < 4; ++cc) {
        int c = wid * 4 + cc;
        async_ld16(&W[(n0 + c * 8 + l8) * DIN + k0 + kk], Bs + c * 1024);
      }
      int q = tid & 15;
#pragma unroll
      for (int p = 0; p < 8; ++p) {
        int row = p * 16 + (tid >> 4);
        const float4 v = *(const float4*)&X[(m0 + row) * DIN + k0 + q * 4];
        union { unsigned int u[2]; uint2 v2; } pk;
        pk.u[0] = pack2_f16(v.x, v.y);
        pk.u[1] = pack2_f16(v.z, v.w);
        *(uint2*)(As + row * 128 + ((q * 8) ^ ((row & 7) << 4))) = pk.v2;
      }
    }
    __syncthreads();
#pragma unroll
    for (int ks = 0; ks < 2; ++ks) {
      int koff = (ks * 64 + g * 16) ^ swz;
      half8 af[4], bf[4];
#pragma unroll
      for (int i = 0; i < 4; ++i)
        af[i] = *(const half8*)(As + (wm * 64 + i * 16 + c15) * 128 + koff);
#pragma unroll
      for (int j = 0; j < 4; ++j)
        bf[j] = *(const half8*)(Bs + (wn * 64 + j * 16 + c15) * 128 + koff);
#pragma unroll
      for (int i = 0; i < 4; ++i)
#pragma unroll
        for (int j = 0; j < 4; ++j)
          acc[i][j] = __builtin_amdgcn_mfma_f32_16x16x32_f16(af[i], bf[j], acc[i][j], 0, 0, 0);
    }
    __syncthreads();
  }

  if (z != 2) {
    f16* dst = (z == 0) ? qb : kb;
#pragma unroll
    for (int i = 0; i < 4; ++i) {
      int mrow = m0 + wm * 64 + i * 16 + 4 * g;
#pragma unroll
      for (int j = 0; j < 4; ++j) {
        int n = n0 + wn * 64 + j * 16 + c15;
        int h = n >> 6, d = n & 63;
#pragma unroll
        for (int r = 0; r < 4; ++r) {
          int m = mrow + r;
          int b = m >> 11, lrow = m & 2047;
          dst[(((b << 4) + h) * 2048 + lrow) * 64 + d] = (f16)(acc[i][j][r] * oscale);
        }
      }
    }
  } else {
    // V^T epilogue: C^T f16 in LDS [128 n][272B], coalesced vtb rows.
#pragma unroll
    for (int i = 0; i < 4; ++i) {
      int mb = (wm * 64 + i * 16 + 4 * g) * 2;
#pragma unroll
      for (int j = 0; j < 4; ++j) {
        int nl = wn * 64 + j * 16 + c15;
        union { unsigned int u[2]; uint2 v; } pk;
        pk.u[0] = pack2_f16(acc[i][j][0], acc[i][j][1]);
        pk.u[1] = pack2_f16(acc[i][j][2], acc[i][j][3]);
        *(uint2*)(smem + nl * 272 + mb) = pk.v;
      }
    }
    __syncthreads();
    int rowp = tid >> 1, halfp = tid & 1;
    int n = n0 + rowp, h = n >> 6, d = n & 63;
    int b = m0 >> 11, lbase = m0 & 2047;
    f16* dstp = vtb + (((size_t)b * 16 + h) * 64 + d) * 2048 + lbase + halfp * 64;
    const char* srcl = smem + rowp * 272 + halfp * 128;
#pragma unroll
    for (int u = 0; u < 8; ++u)
      *(uint4*)(dstp + u * 8) = *(const uint4*)(srcl + u * 16);
  }
}

// --------------------- Kernel 3: flash attention ---------------------------
// R17 structure with KVBLK=256: 4 hb sub-tiles per buffer, 8 tiles, 16
// barriers total (vs R17's 32). LDS 80KB = exactly 2 blocks/CU capacity ==
// supply (grid 512). All sub-layouts identical to R17 (K/V rows, per-hb
// compact swizzled P, monolithic pu softmax — 32 words/qset now).
__global__ void __launch_bounds__(256, 2) kattn(const f16* __restrict__ qb,
                                                const f16* __restrict__ kbuf,
                                                const f16* __restrict__ vt,
                                                float* __restrict__ out) {
  // [0,32768): K [4 hb][64 kv][128B]
  // [32768,65536): V [4 hb][64 d][128B kv]
  // [65536,81920): P [4 w][2 s][16 q][128B] swizzled (Q staging overlay)
  __shared__ __align__(16) char smem[81920];
  char* Qs = smem + 65536;
  float* Ot = (float*)smem;            // epilogue overlay [128 q][68] f32
  float* lsb = (float*)(smem + 34816); // epilogue lsum [128 q] f32

  // XCD swizzle: 512 blocks; id&7 = XCD; 4 heads per XCD (2MB K/V in 4MB L2).
  int id = blockIdx.x;
  int wi = id >> 3;                      // 0..63
  int bh = ((id & 7) << 2) | (wi >> 4);  // 4 heads per XCD
  int q0 = (wi & 15) << 7;               // 16 q-blocks of 128

  int tid = threadIdx.x, lane = tid & 63, w = tid >> 6;
  int c15 = lane & 15, g = lane >> 4;
  int l8 = lane >> 3, l7 = lane & 7;
  int kk = 8 * (l7 ^ l8);
  int swz = (c15 & 7) << 4;

  const f16* kbase = kbuf + (size_t)bh * 2048 * 64;
  const f16* vbase = vt + (size_t)bh * 64 * 2048;

  auto stageK = [&](int kv0) {  // 32 chunks, 8 per wave; rows kv0..kv0+255
#pragma unroll
    for (int cc = 0; cc < 8; ++cc) {
      int c = w * 8 + cc;
      async_ld16(&kbase[(kv0 + c * 8 + l8) * 64 + kk], smem + c * 1024);
    }
  };
  auto stageV = [&](int kv0) {  // [4 hb][64 d][128B]; chunk c: hb=c>>3
#pragma unroll
    for (int cc = 0; cc < 8; ++cc) {
      int c = w * 8 + cc;
      int hb = c >> 3;
      int dv = (c & 7) * 8 + l8;
      async_ld16(&vbase[(size_t)dv * 2048 + kv0 + 64 * hb + kk],
                 smem + 32768 + c * 1024);
    }
  };

  // prologue: Q (16KB, 128 q) + K(0) + V(0)
#pragma unroll
  for (int cc = 0; cc < 4; ++cc) {
    int c = w * 4 + cc;
    async_ld16(&qb[((size_t)bh * 2048 + q0 + c * 8 + l8) * 64 + kk],
               Qs + c * 1024);
  }
  stageK(0);
  stageV(0);
  __syncthreads();
  half8 qf[2][2];  // [q-set][k-slice]; wave w owns q rows w*32..w*32+31
#pragma unroll
  for (int s = 0; s < 2; ++s)
#pragma unroll
    for (int ks = 0; ks < 2; ++ks)
      qf[s][ks] = *(const half8*)(Qs + (w * 32 + s * 16 + c15) * 128 +
                                  ((ks * 64 + g * 16) ^ swz));
  __syncthreads();  // qf reads done before P overlays Qs

  float ls0 = 0.f, ls1 = 0.f;
  floatx4 oacc[2][4] = {};
  char* Pw0 = smem + 65536 + (w * 2 + 0) * 2048 + c15 * 128;
  char* Pw1 = smem + 65536 + (w * 2 + 1) * 2048 + c15 * 128;
  int psw = swz;  // P XOR swizzle

  for (int t = 0; t < 8; ++t) {
    // ---- QK(t): S^T rows kv = 64*hb+16i+4g+r, cols q = w*32+s*16+c15 ----
    floatx4 st[2][16] = {};
    __builtin_amdgcn_s_setprio(1);
#pragma unroll
    for (int hb = 0; hb < 4; ++hb) {
      const char* Ks = smem + hb * 8192;
#pragma unroll
      for (int ks = 0; ks < 2; ++ks) {
        int koff = (ks * 64 + g * 16) ^ swz;
#pragma unroll
        for (int i = 0; i < 4; ++i) {
          half8 kf = *(const half8*)(Ks + (i * 16 + c15) * 128 + koff);
          st[0][hb * 4 + i] = __builtin_amdgcn_mfma_f32_16x16x32_f16(
              kf, qf[0][ks], st[0][hb * 4 + i], 0, 0, 0);
          st[1][hb * 4 + i] = __builtin_amdgcn_mfma_f32_16x16x32_f16(
              kf, qf[1][ks], st[1][hb * 4 + i], 0, 0, 0);
        }
      }
    }
    __builtin_amdgcn_s_setprio(0);
    __syncthreads();  // BAR1: K reads done; V(t) loads drained
    if (t < 7) stageK((t + 1) * 256);  // lands during softmax+PV

    // ---- shift-free softmax, two monolithic blocks (64 values each) ----
    unsigned int pu0[32], pu1[32];
    {
      float ps0 = 0.f, ps1 = 0.f;
#pragma unroll
      for (int x = 0; x < 32; ++x) {
        float p0 = fast_exp2(st[0][x >> 1][(x & 1) * 2]);
        float p1 = fast_exp2(st[0][x >> 1][(x & 1) * 2 + 1]);
        ps0 += p0;
        ps1 += p1;
        pu0[x] = pack2_f16(p0, p1);
      }
      ls0 += ps0 + ps1;
    }
    {
      float ps0 = 0.f, ps1 = 0.f;
#pragma unroll
      for (int x = 0; x < 32; ++x) {
        float p0 = fast_exp2(st[1][x >> 1][(x & 1) * 2]);
        float p1 = fast_exp2(st[1][x >> 1][(x & 1) * 2 + 1]);
        ps0 += p0;
        ps1 += p1;
        pu1[x] = pack2_f16(p0, p1);
      }
      ls1 += ps0 + ps1;
    }

    // ---- PV(t): per hb, write both q-sets' P strips then consume ----
    __builtin_amdgcn_s_setprio(1);
#pragma unroll
    for (int hb = 0; hb < 4; ++hb) {
#pragma unroll
      for (int ii = 0; ii < 4; ++ii) {
        union { unsigned int u[2]; uint2 v; } pk;
        pk.u[0] = pu0[hb * 8 + 2 * ii];
        pk.u[1] = pu0[hb * 8 + 2 * ii + 1];
        *(uint2*)(Pw0 + ((32 * ii + 8 * g) ^ psw)) = pk.v;
        pk.u[0] = pu1[hb * 8 + 2 * ii];
        pk.u[1] = pu1[hb * 8 + 2 * ii + 1];
        *(uint2*)(Pw1 + ((32 * ii + 8 * g) ^ psw)) = pk.v;
      }
      const char* Vs = smem + 32768 + hb * 8192;
#pragma unroll
      for (int kb = 0; kb < 2; ++kb) {
        half8 pf0 = *(const half8*)(Pw0 + ((kb * 64 + 16 * g) ^ psw));
        half8 pf1 = *(const half8*)(Pw1 + ((kb * 64 + 16 * g) ^ psw));
        int koff = (kb * 64 + g * 16) ^ swz;
#pragma unroll
        for (int df = 0; df < 4; ++df) {
          half8 vf = *(const half8*)(Vs + (df * 16 + c15) * 128 + koff);
          oacc[0][df] = __builtin_amdgcn_mfma_f32_16x16x32_f16(vf, pf0, oacc[0][df], 0, 0, 0);
          oacc[1][df] = __builtin_amdgcn_mfma_f32_16x16x32_f16(vf, pf1, oacc[1][df], 0, 0, 0);
        }
      }
    }
    __builtin_amdgcn_s_setprio(0);
    __syncthreads();  // BAR2: V reads done; K(t+1) loads drained
    if (t < 7) stageV((t + 1) * 256);  // lands during next QK
  }

  // lsum reduce over g; lsb[qrow] with qrow = w*32 + s*16 + c15
  ls0 += __shfl_xor(ls0, 16, 64);
  ls0 += __shfl_xor(ls0, 32, 64);
  ls1 += __shfl_xor(ls1, 16, 64);
  ls1 += __shfl_xor(ls1, 32, 64);
  if (g == 0) {
    lsb[w * 32 + c15] = ls0;
    lsb[w * 32 + 16 + c15] = ls1;
  }

  // transpose O^T through LDS (overlay; last BAR2 ordered all loop reads)
#pragma unroll
  for (int s = 0; s < 2; ++s)
#pragma unroll
    for (int df = 0; df < 4; ++df)
      *(floatx4*)&Ot[(w * 32 + s * 16 + c15) * 68 + df * 16 + 4 * g] =
          oacc[s][df];
  __syncthreads();

  int b = bh >> 4, h = bh & 15;
  int row = tid >> 1, seg = tid & 1;  // 2 threads/row, 32 floats each
  float inv = 1.f / lsb[row];
  float* dstp = &out[((size_t)b * 2048 + q0 + row) * 1024 + h * 64 + seg * 32];
  const float* srcl = &Ot[row * 68 + seg * 32];
#pragma unroll
  for (int u = 0; u < 8; ++u) {
    floatx4 v = *(const floatx4*)(srcl + u * 4) * inv;
    *(floatx4*)(dstp + u * 4) = v;
  }
}

// ---------------------------------------------------------------------------
extern "C" void kernel_launch(void* const* d_in, const int* in_sizes, int n_in,
                              void* d_out, int out_size, void* d_ws, size_t ws_size,
                              hipStream_t stream) {
  const float* xq = (const float*)d_in[0];
  const float* xk = (const float*)d_in[1];
  const float* wq = (const float*)d_in[2];
  const float* wk = (const float*)d_in[3];
  const float* wv = (const float*)d_in[4];
  char* ws = (char*)d_ws;
  f16* wqt = (f16*)(ws + (0ull << 20));
  f16* wkt = (f16*)(ws + (2ull << 20));
  f16* wvt = (f16*)(ws + (4ull << 20));

  bool fit = ws_size >= (46ull << 20);
  f16 *xqh, *xkh, *qbuf, *kbuf, *vtb;
  if (fit) {
    xqh  = (f16*)(ws + (6ull << 20));
    xkh  = (f16*)(ws + (14ull << 20));
    qbuf = (f16*)(ws + (22ull << 20));
    kbuf = (f16*)(ws + (30ull << 20));
    vtb  = (f16*)(ws + (38ull << 20));
  } else {
    xqh = xkh = nullptr;
    qbuf = (f16*)(ws + (6ull << 20));
    kbuf = (f16*)(ws + (14ull << 20));
    vtb  = (f16*)(ws + (22ull << 20));
  }

  kprep<<<dim3(32, 32, fit ? 5 : 3), 256, 0, stream>>>(xq, xk, wq, wk, wv,
                                                       wqt, wkt, wvt, xqh, xkh);
  if (fit) {
    kproj<1><<<dim3(8, 32, 3), 256, 0, stream>>>(xq, xk, xqh, xkh, wqt, wkt,
                                                 wvt, qbuf, kbuf, vtb);
  } else {
    kproj<0><<<dim3(8, 32, 3), 256, 0, stream>>>(xq, xk, xqh, xkh, wqt, wkt,
                                                 wvt, qbuf, kbuf, vtb);
  }
  kattn<<<512, 256, 0, stream>>>(qbuf, kbuf, vtb, (float*)d_out);
}

// Round 21
// 118.623 us; speedup vs baseline: 1.1173x; 1.1173x over previous
//
#include <hip/hip_runtime.h>

#define DIN 1024
#define LSEQ 2048

typedef _Float16 f16;
typedef _Float16 half8 __attribute__((ext_vector_type(8)));
typedef float floatx4 __attribute__((ext_vector_type(4)));

__device__ __forceinline__ void async_ld16(const void* g, void* l) {
  __builtin_amdgcn_global_load_lds(
      (const __attribute__((address_space(1))) void*)g,
      (__attribute__((address_space(3))) void*)l, 16, 0, 0);
}

__device__ __forceinline__ float fast_exp2(float x) {
#if __has_builtin(__builtin_amdgcn_exp2f)
  return __builtin_amdgcn_exp2f(x);
#else
  return exp2f(x);
#endif
}

__device__ __forceinline__ unsigned int pack2_f16(float a, float b) {
#if __has_builtin(__builtin_amdgcn_cvt_pkrtz)
  typedef __fp16 fp16x2 __attribute__((ext_vector_type(2)));
  fp16x2 h = __builtin_amdgcn_cvt_pkrtz(a, b);
  return __builtin_bit_cast(unsigned int, h);
#else
  union { f16 h[2]; unsigned int u; } pk;
  pk.h[0] = (f16)a; pk.h[1] = (f16)b;
  return pk.u;
#endif
}

// ------- Kernel 1: fused prep. z<3: W [k][n] fp32 -> Wt [n][k] f16;
//                   z=3,4: X fp32 -> f16 elementwise cast. -----------------
__global__ void __launch_bounds__(256) kprep(const float* __restrict__ xq,
                                             const float* __restrict__ xk,
                                             const float* __restrict__ wq,
                                             const float* __restrict__ wk,
                                             const float* __restrict__ wv,
                                             f16* __restrict__ wqt,
                                             f16* __restrict__ wkt,
                                             f16* __restrict__ wvt,
                                             f16* __restrict__ xqh,
                                             f16* __restrict__ xkh) {
  int z = blockIdx.z;
  int tid = threadIdx.x;
  if (z < 3) {
    __shared__ float t[32][33];
    const float* src = z == 0 ? wq : (z == 1 ? wk : wv);
    f16* dst = z == 0 ? wqt : (z == 1 ? wkt : wvt);
    int k0 = blockIdx.x * 32, n0 = blockIdx.y * 32;
    int tx = tid & 31, ty = tid >> 5;  // 32 x 8
#pragma unroll
    for (int r = 0; r < 4; ++r)
      t[ty + r * 8][tx] = src[(k0 + ty + r * 8) * DIN + n0 + tx];
    __syncthreads();
#pragma unroll
    for (int r = 0; r < 4; ++r)
      dst[(n0 + ty + r * 8) * DIN + k0 + tx] = (f16)t[tx][ty + r * 8];
  } else {
    const float4* src = (const float4*)(z == 4 ? xk : xq);
    uint2* dst = (uint2*)(z == 4 ? xkh : xqh);
    int bx = blockIdx.y * 32 + blockIdx.x;  // 0..1023
    int i = bx * 256 + tid;
#pragma unroll
    for (int it = 0; it < 4; ++it, i += 262144) {
      float4 v = src[i];
      union { unsigned int u[2]; uint2 w; } pk;
      pk.u[0] = pack2_f16(v.x, v.y);
      pk.u[1] = pack2_f16(v.z, v.w);
      dst[i] = pk.w;
    }
  }
}

// ------------- Kernel 2: C = X(4096x1024) @ W -> Q/K fp16, V^T fp16 --------
template <int AMODE>
__global__ void __launch_bounds__(256) kproj(const float* __restrict__ xq,
                                             const float* __restrict__ xk,
                                             const f16* __restrict__ xqh,
                                             const f16* __restrict__ xkh,
                                             const f16* __restrict__ wqt,
                                             const f16* __restrict__ wkt,
                                             const f16* __restrict__ wvt,
                                             f16* __restrict__ qb,
                                             f16* __restrict__ kb,
                                             f16* __restrict__ vtb) {
  __shared__ __align__(16) char smem[34816];  // As 16K | Bs 16K ; z=2 epilogue
  char* As = smem;
  char* Bs = smem + 16384;
  const float* X;
  const f16* Xh;
  const f16* W;
  int z = blockIdx.z;
  if (z == 0) { X = xq; Xh = xqh; W = wqt; }
  else if (z == 1) { X = xk; Xh = xkh; W = wkt; }
  else { X = xk; Xh = xkh; W = wvt; }
  float oscale = (z == 0) ? 0.18033688011112042f : 1.0f;  // SC only for Q
  int m0 = blockIdx.y * 128, n0 = blockIdx.x * 128;
  int tid = threadIdx.x, lane = tid & 63, wid = tid >> 6;
  int wm = wid >> 1, wn = wid & 1;
  int c15 = lane & 15, g = lane >> 4;
  int l8 = lane >> 3, l7 = lane & 7;
  int kk = 8 * (l7 ^ l8);
  int swz = (c15 & 7) << 4;
  floatx4 acc[4][4] = {};

  for (int kt = 0; kt < 16; ++kt) {
    int k0 = kt * 64;
    if constexpr (AMODE == 1) {
#pragma unroll
      for (int cc = 0; cc < 4; ++cc) {
        int c = wid * 4 + cc;
        async_ld16(&Xh[(m0 + c * 8 + l8) * DIN + k0 + kk], As + c * 1024);
        async_ld16(&W[(n0 + c * 8 + l8) * DIN + k0 + kk], Bs + c * 1024);
      }
    } else {
#pragma unroll
      for (int cc = 0; cc < 4; ++cc) {
        int c = wid * 4 + cc;
        async_ld16(&W[(n0 + c * 8 + l8) * DIN + k0 + kk], Bs + c * 1024);
      }
      int q = tid & 15;
#pragma unroll
      for (int p = 0; p < 8; ++p) {
        int row = p * 16 + (tid >> 4);
        const float4 v = *(const float4*)&X[(m0 + row) * DIN + k0 + q * 4];
        union { unsigned int u[2]; uint2 v2; } pk;
        pk.u[0] = pack2_f16(v.x, v.y);
        pk.u[1] = pack2_f16(v.z, v.w);
        *(uint2*)(As + row * 128 + ((q * 8) ^ ((row & 7) << 4))) = pk.v2;
      }
    }
    __syncthreads();
#pragma unroll
    for (int ks = 0; ks < 2; ++ks) {
      int koff = (ks * 64 + g * 16) ^ swz;
      half8 af[4], bf[4];
#pragma unroll
      for (int i = 0; i < 4; ++i)
        af[i] = *(const half8*)(As + (wm * 64 + i * 16 + c15) * 128 + koff);
#pragma unroll
      for (int j = 0; j < 4; ++j)
        bf[j] = *(const half8*)(Bs + (wn * 64 + j * 16 + c15) * 128 + koff);
#pragma unroll
      for (int i = 0; i < 4; ++i)
#pragma unroll
        for (int j = 0; j < 4; ++j)
          acc[i][j] = __builtin_amdgcn_mfma_f32_16x16x32_f16(af[i], bf[j], acc[i][j], 0, 0, 0);
    }
    __syncthreads();
  }

  if (z != 2) {
    f16* dst = (z == 0) ? qb : kb;
#pragma unroll
    for (int i = 0; i < 4; ++i) {
      int mrow = m0 + wm * 64 + i * 16 + 4 * g;
#pragma unroll
      for (int j = 0; j < 4; ++j) {
        int n = n0 + wn * 64 + j * 16 + c15;
        int h = n >> 6, d = n & 63;
#pragma unroll
        for (int r = 0; r < 4; ++r) {
          int m = mrow + r;
          int b = m >> 11, lrow = m & 2047;
          dst[(((b << 4) + h) * 2048 + lrow) * 64 + d] = (f16)(acc[i][j][r] * oscale);
        }
      }
    }
  } else {
    // V^T epilogue: C^T f16 in LDS [128 n][272B], coalesced vtb rows.
#pragma unroll
    for (int i = 0; i < 4; ++i) {
      int mb = (wm * 64 + i * 16 + 4 * g) * 2;
#pragma unroll
      for (int j = 0; j < 4; ++j) {
        int nl = wn * 64 + j * 16 + c15;
        union { unsigned int u[2]; uint2 v; } pk;
        pk.u[0] = pack2_f16(acc[i][j][0], acc[i][j][1]);
        pk.u[1] = pack2_f16(acc[i][j][2], acc[i][j][3]);
        *(uint2*)(smem + nl * 272 + mb) = pk.v;
      }
    }
    __syncthreads();
    int rowp = tid >> 1, halfp = tid & 1;
    int n = n0 + rowp, h = n >> 6, d = n & 63;
    int b = m0 >> 11, lbase = m0 & 2047;
    f16* dstp = vtb + (((size_t)b * 16 + h) * 64 + d) * 2048 + lbase + halfp * 64;
    const char* srcl = smem + rowp * 272 + halfp * 128;
#pragma unroll
    for (int u = 0; u < 8; ++u)
      *(uint4*)(dstp + u * 8) = *(const uint4*)(srcl + u * 16);
  }
}

// --------------------- Kernel 3: flash attention ---------------------------
// KVBLK=256 with SPLIT-HALF schedule (spill-free): per 256-kv tile, two
// 128-kv halves each with R17's exact register profile (st[2][8], pu[16]x2).
// 2 barriers per 256 kv (half R17's rate). Staging windows:
//   QK(h0) SM(0) PV(h0) QK(h1) | BAR1 | stageK(t+1)+stageV01(t+1) SM(1)
//   PV(h1) | BAR2 | stageV23(t+1)
// K(t+1) & V01(t+1) drain at BAR2(t) before QK/PV(t+1,h0); V23(t+1) drains
// at BAR1(t+1) before PV(t+1,h1). LDS 80KB = 2 blocks/CU == supply.
__global__ void __launch_bounds__(256, 2) kattn(const f16* __restrict__ qb,
                                                const f16* __restrict__ kbuf,
                                                const f16* __restrict__ vt,
                                                float* __restrict__ out) {
  // [0,32768): K [4 hb][64 kv][128B]
  // [32768,65536): V [4 hb][64 d][128B kv]
  // [65536,81920): P [4 w][2 s][16 q][128B] swizzled (Q staging overlay)
  __shared__ __align__(16) char smem[81920];
  char* Qs = smem + 65536;
  float* Ot = (float*)smem;            // epilogue overlay [128 q][68] f32
  float* lsb = (float*)(smem + 34816); // epilogue lsum [128 q] f32

  // XCD swizzle: 512 blocks; id&7 = XCD; 4 heads per XCD (2MB K/V in 4MB L2).
  int id = blockIdx.x;
  int wi = id >> 3;                      // 0..63
  int bh = ((id & 7) << 2) | (wi >> 4);  // 4 heads per XCD
  int q0 = (wi & 15) << 7;               // 16 q-blocks of 128

  int tid = threadIdx.x, lane = tid & 63, w = tid >> 6;
  int c15 = lane & 15, g = lane >> 4;
  int l8 = lane >> 3, l7 = lane & 7;
  int kk = 8 * (l7 ^ l8);
  int swz = (c15 & 7) << 4;

  const f16* kbase = kbuf + (size_t)bh * 2048 * 64;
  const f16* vbase = vt + (size_t)bh * 64 * 2048;

  auto stageK = [&](int kv0) {  // 32 chunks, 8 per wave; rows kv0..kv0+255
#pragma unroll
    for (int cc = 0; cc < 8; ++cc) {
      int c = w * 8 + cc;
      async_ld16(&kbase[(kv0 + c * 8 + l8) * 64 + kk], smem + c * 1024);
    }
  };
  auto stageVh = [&](int kv0, int cbase) {  // hb pair: cbase=0 -> hb0,1;
                                            // cbase=16 -> hb2,3 (4 ch/wave)
#pragma unroll
    for (int cc = 0; cc < 4; ++cc) {
      int c = cbase + w * 4 + cc;
      int hb = c >> 3;
      int dv = (c & 7) * 8 + l8;
      async_ld16(&vbase[(size_t)dv * 2048 + kv0 + 64 * hb + kk],
                 smem + 32768 + c * 1024);
    }
  };

  // prologue: Q (16KB, 128 q) + K(0) + V(0) full
#pragma unroll
  for (int cc = 0; cc < 4; ++cc) {
    int c = w * 4 + cc;
    async_ld16(&qb[((size_t)bh * 2048 + q0 + c * 8 + l8) * 64 + kk],
               Qs + c * 1024);
  }
  stageK(0);
  stageVh(0, 0);
  stageVh(0, 16);
  __syncthreads();
  half8 qf[2][2];  // [q-set][k-slice]; wave w owns q rows w*32..w*32+31
#pragma unroll
  for (int s = 0; s < 2; ++s)
#pragma unroll
    for (int ks = 0; ks < 2; ++ks)
      qf[s][ks] = *(const half8*)(Qs + (w * 32 + s * 16 + c15) * 128 +
                                  ((ks * 64 + g * 16) ^ swz));
  __syncthreads();  // qf reads done before P overlays Qs

  float ls0 = 0.f, ls1 = 0.f;
  floatx4 oacc[2][4] = {};
  char* Pw0 = smem + 65536 + (w * 2 + 0) * 2048 + c15 * 128;
  char* Pw1 = smem + 65536 + (w * 2 + 1) * 2048 + c15 * 128;
  int psw = swz;  // P XOR swizzle

  for (int t = 0; t < 8; ++t) {
#pragma unroll
    for (int half = 0; half < 2; ++half) {
      // ---- QK(half): K hb = half*2 + {0,1}; R17 register shape ----
      floatx4 st[2][8] = {};
      __builtin_amdgcn_s_setprio(1);
#pragma unroll
      for (int h2 = 0; h2 < 2; ++h2) {
        const char* Ks = smem + (half * 2 + h2) * 8192;
#pragma unroll
        for (int ks = 0; ks < 2; ++ks) {
          int koff = (ks * 64 + g * 16) ^ swz;
#pragma unroll
          for (int i = 0; i < 4; ++i) {
            half8 kf = *(const half8*)(Ks + (i * 16 + c15) * 128 + koff);
            st[0][h2 * 4 + i] = __builtin_amdgcn_mfma_f32_16x16x32_f16(
                kf, qf[0][ks], st[0][h2 * 4 + i], 0, 0, 0);
            st[1][h2 * 4 + i] = __builtin_amdgcn_mfma_f32_16x16x32_f16(
                kf, qf[1][ks], st[1][h2 * 4 + i], 0, 0, 0);
          }
        }
      }
      __builtin_amdgcn_s_setprio(0);

      if (half == 1) {
        __syncthreads();  // BAR1: all K(t) reads + V01(t) reads done
        if (t < 7) {
          stageK((t + 1) * 256);        // drains at BAR2(t)
          stageVh((t + 1) * 256, 0);    // V01(t+1), drains at BAR2(t)
        }
      }

      // ---- shift-free softmax, two R12-shape monolithic blocks ----
      unsigned int pu0[16], pu1[16];
      {
        float ps0 = 0.f, ps1 = 0.f;
#pragma unroll
        for (int x = 0; x < 16; ++x) {
          float p0 = fast_exp2(st[0][x >> 1][(x & 1) * 2]);
          float p1 = fast_exp2(st[0][x >> 1][(x & 1) * 2 + 1]);
          ps0 += p0;
          ps1 += p1;
          pu0[x] = pack2_f16(p0, p1);
        }
        ls0 += ps0 + ps1;
      }
      {
        float ps0 = 0.f, ps1 = 0.f;
#pragma unroll
        for (int x = 0; x < 16; ++x) {
          float p0 = fast_exp2(st[1][x >> 1][(x & 1) * 2]);
          float p1 = fast_exp2(st[1][x >> 1][(x & 1) * 2 + 1]);
          ps0 += p0;
          ps1 += p1;
          pu1[x] = pack2_f16(p0, p1);
        }
        ls1 += ps0 + ps1;
      }

      // ---- PV(half): per hb, write both q-sets' P strips then consume ----
      __builtin_amdgcn_s_setprio(1);
#pragma unroll
      for (int h2 = 0; h2 < 2; ++h2) {
#pragma unroll
        for (int ii = 0; ii < 4; ++ii) {
          union { unsigned int u[2]; uint2 v; } pk;
          pk.u[0] = pu0[h2 * 8 + 2 * ii];
          pk.u[1] = pu0[h2 * 8 + 2 * ii + 1];
          *(uint2*)(Pw0 + ((32 * ii + 8 * g) ^ psw)) = pk.v;
          pk.u[0] = pu1[h2 * 8 + 2 * ii];
          pk.u[1] = pu1[h2 * 8 + 2 * ii + 1];
          *(uint2*)(Pw1 + ((32 * ii + 8 * g) ^ psw)) = pk.v;
        }
        const char* Vs = smem + 32768 + (half * 2 + h2) * 8192;
#pragma unroll
        for (int kb = 0; kb < 2; ++kb) {
          half8 pf0 = *(const half8*)(Pw0 + ((kb * 64 + 16 * g) ^ psw));
          half8 pf1 = *(const half8*)(Pw1 + ((kb * 64 + 16 * g) ^ psw));
          int koff = (kb * 64 + g * 16) ^ swz;
#pragma unroll
          for (int df = 0; df < 4; ++df) {
            half8 vf = *(const half8*)(Vs + (df * 16 + c15) * 128 + koff);
            oacc[0][df] = __builtin_amdgcn_mfma_f32_16x16x32_f16(vf, pf0, oacc[0][df], 0, 0, 0);
            oacc[1][df] = __builtin_amdgcn_mfma_f32_16x16x32_f16(vf, pf1, oacc[1][df], 0, 0, 0);
          }
        }
      }
      __builtin_amdgcn_s_setprio(0);
    }
    __syncthreads();  // BAR2: all V(t) reads done; K(t+1)+V01(t+1) drained
    if (t < 7) stageVh((t + 1) * 256, 16);  // V23(t+1), drains at BAR1(t+1)
  }

  // lsum reduce over g; lsb[qrow] with qrow = w*32 + s*16 + c15
  ls0 += __shfl_xor(ls0, 16, 64);
  ls0 += __shfl_xor(ls0, 32, 64);
  ls1 += __shfl_xor(ls1, 16, 64);
  ls1 += __shfl_xor(ls1, 32, 64);
  if (g == 0) {
    lsb[w * 32 + c15] = ls0;
    lsb[w * 32 + 16 + c15] = ls1;
  }

  // transpose O^T through LDS (overlay; last BAR2 ordered all loop reads)
#pragma unroll
  for (int s = 0; s < 2; ++s)
#pragma unroll
    for (int df = 0; df < 4; ++df)
      *(floatx4*)&Ot[(w * 32 + s * 16 + c15) * 68 + df * 16 + 4 * g] =
          oacc[s][df];
  __syncthreads();

  int b = bh >> 4, h = bh & 15;
  int row = tid >> 1, seg = tid & 1;  // 2 threads/row, 32 floats each
  float inv = 1.f / lsb[row];
  float* dstp = &out[((size_t)b * 2048 + q0 + row) * 1024 + h * 64 + seg * 32];
  const float* srcl = &Ot[row * 68 + seg * 32];
#pragma unroll
  for (int u = 0; u < 8; ++u) {
    floatx4 v = *(const floatx4*)(srcl + u * 4) * inv;
    *(floatx4*)(dstp + u * 4) = v;
  }
}

// ---------------------------------------------------------------------------
extern "C" void kernel_launch(void* const* d_in, const int* in_sizes, int n_in,
                              void* d_out, int out_size, void* d_ws, size_t ws_size,
                              hipStream_t stream) {
  const float* xq = (const float*)d_in[0];
  const float* xk = (const float*)d_in[1];
  const float* wq = (const float*)d_in[2];
  const float* wk = (const float*)d_in[3];
  const float* wv = (const float*)d_in[4];
  char* ws = (char*)d_ws;
  f16* wqt = (f16*)(ws + (0ull << 20));
  f16* wkt = (f16*)(ws + (2ull << 20));
  f16* wvt = (f16*)(ws + (4ull << 20));

  bool fit = ws_size >= (46ull << 20);
  f16 *xqh, *xkh, *qbuf, *kbuf, *vtb;
  if (fit) {
    xqh  = (f16*)(ws + (6ull << 20));
    xkh  = (f16*)(ws + (14ull << 20));
    qbuf = (f16*)(ws + (22ull << 20));
    kbuf = (f16*)(ws + (30ull << 20));
    vtb  = (f16*)(ws + (38ull << 20));
  } else {
    xqh = xkh = nullptr;
    qbuf = (f16*)(ws + (6ull << 20));
    kbuf = (f16*)(ws + (14ull << 20));
    vtb  = (f16*)(ws + (22ull << 20));
  }

  kprep<<<dim3(32, 32, fit ? 5 : 3), 256, 0, stream>>>(xq, xk, wq, wk, wv,
                                                       wqt, wkt, wvt, xqh, xkh);
  if (fit) {
    kproj<1><<<dim3(8, 32, 3), 256, 0, stream>>>(xq, xk, xqh, xkh, wqt, wkt,
                                                 wvt, qbuf, kbuf, vtb);
  } else {
    kproj<0><<<dim3(8, 32, 3), 256, 0, stream>>>(xq, xk, xqh, xkh, wqt, wkt,
                                                 wvt, qbuf, kbuf, vtb);
  }
  kattn<<<512, 256, 0, stream>>>(qbuf, kbuf, vtb, (float*)d_out);
}

// Round 22
// 102.104 us; speedup vs baseline: 1.2980x; 1.1618x over previous
//
#include <hip/hip_runtime.h>

#define DIN 1024
#define LSEQ 2048

typedef _Float16 f16;
typedef _Float16 half8 __attribute__((ext_vector_type(8)));
typedef float floatx4 __attribute__((ext_vector_type(4)));

__device__ __forceinline__ void async_ld16(const void* g, void* l) {
  __builtin_amdgcn_global_load_lds(
      (const __attribute__((address_space(1))) void*)g,
      (__attribute__((address_space(3))) void*)l, 16, 0, 0);
}

__device__ __forceinline__ float fast_exp2(float x) {
#if __has_builtin(__builtin_amdgcn_exp2f)
  return __builtin_amdgcn_exp2f(x);
#else
  return exp2f(x);
#endif
}

__device__ __forceinline__ unsigned int pack2_f16(float a, float b) {
#if __has_builtin(__builtin_amdgcn_cvt_pkrtz)
  typedef __fp16 fp16x2 __attribute__((ext_vector_type(2)));
  fp16x2 h = __builtin_amdgcn_cvt_pkrtz(a, b);
  return __builtin_bit_cast(unsigned int, h);
#else
  union { f16 h[2]; unsigned int u; } pk;
  pk.h[0] = (f16)a; pk.h[1] = (f16)b;
  return pk.u;
#endif
}

// ------- Kernel 1: fused prep. z<3: W [k][n] fp32 -> Wt [n][k] f16;
//                   z=3,4: X fp32 -> f16 elementwise cast. -----------------
__global__ void __launch_bounds__(256) kprep(const float* __restrict__ xq,
                                             const float* __restrict__ xk,
                                             const float* __restrict__ wq,
                                             const float* __restrict__ wk,
                                             const float* __restrict__ wv,
                                             f16* __restrict__ wqt,
                                             f16* __restrict__ wkt,
                                             f16* __restrict__ wvt,
                                             f16* __restrict__ xqh,
                                             f16* __restrict__ xkh) {
  int z = blockIdx.z;
  int tid = threadIdx.x;
  if (z < 3) {
    __shared__ float t[32][33];
    const float* src = z == 0 ? wq : (z == 1 ? wk : wv);
    f16* dst = z == 0 ? wqt : (z == 1 ? wkt : wvt);
    int k0 = blockIdx.x * 32, n0 = blockIdx.y * 32;
    int tx = tid & 31, ty = tid >> 5;  // 32 x 8
#pragma unroll
    for (int r = 0; r < 4; ++r)
      t[ty + r * 8][tx] = src[(k0 + ty + r * 8) * DIN + n0 + tx];
    __syncthreads();
#pragma unroll
    for (int r = 0; r < 4; ++r)
      dst[(n0 + ty + r * 8) * DIN + k0 + tx] = (f16)t[tx][ty + r * 8];
  } else {
    const float4* src = (const float4*)(z == 4 ? xk : xq);
    uint2* dst = (uint2*)(z == 4 ? xkh : xqh);
    int bx = blockIdx.y * 32 + blockIdx.x;  // 0..1023
    int i = bx * 256 + tid;
#pragma unroll
    for (int it = 0; it < 4; ++it, i += 262144) {
      float4 v = src[i];
      union { unsigned int u[2]; uint2 w; } pk;
      pk.u[0] = pack2_f16(v.x, v.y);
      pk.u[1] = pack2_f16(v.z, v.w);
      dst[i] = pk.w;
    }
  }
}

// ------------- Kernel 2: C = X(4096x1024) @ W -> Q/K fp16, V^T fp16 --------
template <int AMODE>
__global__ void __launch_bounds__(256) kproj(const float* __restrict__ xq,
                                             const float* __restrict__ xk,
                                             const f16* __restrict__ xqh,
                                             const f16* __restrict__ xkh,
                                             const f16* __restrict__ wqt,
                                             const f16* __restrict__ wkt,
                                             const f16* __restrict__ wvt,
                                             f16* __restrict__ qb,
                                             f16* __restrict__ kb,
                                             f16* __restrict__ vtb) {
  __shared__ __align__(16) char smem[34816];  // As 16K | Bs 16K ; z=2 epilogue
  char* As = smem;
  char* Bs = smem + 16384;
  const float* X;
  const f16* Xh;
  const f16* W;
  int z = blockIdx.z;
  if (z == 0) { X = xq; Xh = xqh; W = wqt; }
  else if (z == 1) { X = xk; Xh = xkh; W = wkt; }
  else { X = xk; Xh = xkh; W = wvt; }
  float oscale = (z == 0) ? 0.18033688011112042f : 1.0f;  // SC only for Q
  int m0 = blockIdx.y * 128, n0 = blockIdx.x * 128;
  int tid = threadIdx.x, lane = tid & 63, wid = tid >> 6;
  int wm = wid >> 1, wn = wid & 1;
  int c15 = lane & 15, g = lane >> 4;
  int l8 = lane >> 3, l7 = lane & 7;
  int kk = 8 * (l7 ^ l8);
  int swz = (c15 & 7) << 4;
  floatx4 acc[4][4] = {};

  for (int kt = 0; kt < 16; ++kt) {
    int k0 = kt * 64;
    if constexpr (AMODE == 1) {
#pragma unroll
      for (int cc = 0; cc < 4; ++cc) {
        int c = wid * 4 + cc;
        async_ld16(&Xh[(m0 + c * 8 + l8) * DIN + k0 + kk], As + c * 1024);
        async_ld16(&W[(n0 + c * 8 + l8) * DIN + k0 + kk], Bs + c * 1024);
      }
    } else {
#pragma unroll
      for (int cc = 0; cc < 4; ++cc) {
        int c = wid * 4 + cc;
        async_ld16(&W[(n0 + c * 8 + l8) * DIN + k0 + kk], Bs + c * 1024);
      }
      int q = tid & 15;
#pragma unroll
      for (int p = 0; p < 8; ++p) {
        int row = p * 16 + (tid >> 4);
        const float4 v = *(const float4*)&X[(m0 + row) * DIN + k0 + q * 4];
        union { unsigned int u[2]; uint2 v2; } pk;
        pk.u[0] = pack2_f16(v.x, v.y);
        pk.u[1] = pack2_f16(v.z, v.w);
        *(uint2*)(As + row * 128 + ((q * 8) ^ ((row & 7) << 4))) = pk.v2;
      }
    }
    __syncthreads();
#pragma unroll
    for (int ks = 0; ks < 2; ++ks) {
      int koff = (ks * 64 + g * 16) ^ swz;
      half8 af[4], bf[4];
#pragma unroll
      for (int i = 0; i < 4; ++i)
        af[i] = *(const half8*)(As + (wm * 64 + i * 16 + c15) * 128 + koff);
#pragma unroll
      for (int j = 0; j < 4; ++j)
        bf[j] = *(const half8*)(Bs + (wn * 64 + j * 16 + c15) * 128 + koff);
#pragma unroll
      for (int i = 0; i < 4; ++i)
#pragma unroll
        for (int j = 0; j < 4; ++j)
          acc[i][j] = __builtin_amdgcn_mfma_f32_16x16x32_f16(af[i], bf[j], acc[i][j], 0, 0, 0);
    }
    __syncthreads();
  }

  if (z != 2) {
    f16* dst = (z == 0) ? qb : kb;
#pragma unroll
    for (int i = 0; i < 4; ++i) {
      int mrow = m0 + wm * 64 + i * 16 + 4 * g;
#pragma unroll
      for (int j = 0; j < 4; ++j) {
        int n = n0 + wn * 64 + j * 16 + c15;
        int h = n >> 6, d = n & 63;
#pragma unroll
        for (int r = 0; r < 4; ++r) {
          int m = mrow + r;
          int b = m >> 11, lrow = m & 2047;
          dst[(((b << 4) + h) * 2048 + lrow) * 64 + d] = (f16)(acc[i][j][r] * oscale);
        }
      }
    }
  } else {
    // V^T epilogue: C^T f16 in LDS [128 n][272B], coalesced vtb rows.
#pragma unroll
    for (int i = 0; i < 4; ++i) {
      int mb = (wm * 64 + i * 16 + 4 * g) * 2;
#pragma unroll
      for (int j = 0; j < 4; ++j) {
        int nl = wn * 64 + j * 16 + c15;
        union { unsigned int u[2]; uint2 v; } pk;
        pk.u[0] = pack2_f16(acc[i][j][0], acc[i][j][1]);
        pk.u[1] = pack2_f16(acc[i][j][2], acc[i][j][3]);
        *(uint2*)(smem + nl * 272 + mb) = pk.v;
      }
    }
    __syncthreads();
    int rowp = tid >> 1, halfp = tid & 1;
    int n = n0 + rowp, h = n >> 6, d = n & 63;
    int b = m0 >> 11, lbase = m0 & 2047;
    f16* dstp = vtb + (((size_t)b * 16 + h) * 64 + d) * 2048 + lbase + halfp * 64;
    const char* srcl = smem + rowp * 272 + halfp * 128;
#pragma unroll
    for (int u = 0; u < 8; ++u)
      *(uint4*)(dstp + u * 8) = *(const uint4*)(srcl + u * 16);
  }
}

// --------------------- Kernel 3: flash attention (R17 exact, best 54.5us) --
// 4 waves x 2 q-sets (32 q/wave), 128 q/block, grid 512, KVBLK=128,
// single-buffer 2-barrier pipeline, per-hb compact swizzled P.
__global__ void __launch_bounds__(256, 2) kattn(const f16* __restrict__ qb,
                                                const f16* __restrict__ kbuf,
                                                const f16* __restrict__ vt,
                                                float* __restrict__ out) {
  // [0,16384): K [2 hb][64 kv][128B]
  // [16384,32768): V [2 hb][64 d][128B kv]
  // [32768,49152): P [4 w][2 s][16 q][128B] swizzled (Q staging overlay)
  __shared__ __align__(16) char smem[49152];
  char* Qs = smem + 32768;
  float* Ot = (float*)smem;            // epilogue overlay [128 q][68] f32
  float* lsb = (float*)(smem + 34816); // epilogue lsum [128 q] f32

  // XCD swizzle: 512 blocks; id&7 = XCD; 4 heads per XCD (2MB K/V in 4MB L2).
  int id = blockIdx.x;
  int wi = id >> 3;                      // 0..63
  int bh = ((id & 7) << 2) | (wi >> 4);  // 4 heads per XCD
  int q0 = (wi & 15) << 7;               // 16 q-blocks of 128

  int tid = threadIdx.x, lane = tid & 63, w = tid >> 6;
  int c15 = lane & 15, g = lane >> 4;
  int l8 = lane >> 3, l7 = lane & 7;
  int kk = 8 * (l7 ^ l8);
  int swz = (c15 & 7) << 4;

  const f16* kbase = kbuf + (size_t)bh * 2048 * 64;
  const f16* vbase = vt + (size_t)bh * 64 * 2048;

  auto stageK = [&](int kv0) {  // 16 chunks, 4 per wave; rows kv0..kv0+127
#pragma unroll
    for (int cc = 0; cc < 4; ++cc) {
      int c = w * 4 + cc;
      async_ld16(&kbase[(kv0 + c * 8 + l8) * 64 + kk], smem + c * 1024);
    }
  };
  auto stageV = [&](int kv0) {  // [2 hb][64 d][128B]; chunk c: hb=c>>3
#pragma unroll
    for (int cc = 0; cc < 4; ++cc) {
      int c = w * 4 + cc;
      int hb = c >> 3;
      int dv = (c & 7) * 8 + l8;
      async_ld16(&vbase[(size_t)dv * 2048 + kv0 + 64 * hb + kk],
                 smem + 16384 + c * 1024);
    }
  };

  // prologue: Q (16KB, 128 q) + K(0) + V(0)
#pragma unroll
  for (int cc = 0; cc < 4; ++cc) {
    int c = w * 4 + cc;
    async_ld16(&qb[((size_t)bh * 2048 + q0 + c * 8 + l8) * 64 + kk],
               Qs + c * 1024);
  }
  stageK(0);
  stageV(0);
  __syncthreads();
  half8 qf[2][2];  // [q-set][k-slice]; wave w owns q rows w*32..w*32+31
#pragma unroll
  for (int s = 0; s < 2; ++s)
#pragma unroll
    for (int ks = 0; ks < 2; ++ks)
      qf[s][ks] = *(const half8*)(Qs + (w * 32 + s * 16 + c15) * 128 +
                                  ((ks * 64 + g * 16) ^ swz));
  __syncthreads();  // qf reads done before P overlays Qs

  float ls0 = 0.f, ls1 = 0.f;
  floatx4 oacc[2][4] = {};
  char* Pw0 = smem + 32768 + (w * 2 + 0) * 2048 + c15 * 128;
  char* Pw1 = smem + 32768 + (w * 2 + 1) * 2048 + c15 * 128;
  int psw = swz;  // P XOR swizzle

  for (int t = 0; t < 16; ++t) {
    // ---- QK(t): S^T rows kv = 64*hb+16i+4g+r, cols q = w*32+s*16+c15 ----
    floatx4 st[2][8] = {};
    __builtin_amdgcn_s_setprio(1);
#pragma unroll
    for (int hb = 0; hb < 2; ++hb) {
      const char* Ks = smem + hb * 8192;
#pragma unroll
      for (int ks = 0; ks < 2; ++ks) {
        int koff = (ks * 64 + g * 16) ^ swz;
#pragma unroll
        for (int i = 0; i < 4; ++i) {
          half8 kf = *(const half8*)(Ks + (i * 16 + c15) * 128 + koff);
          st[0][hb * 4 + i] = __builtin_amdgcn_mfma_f32_16x16x32_f16(
              kf, qf[0][ks], st[0][hb * 4 + i], 0, 0, 0);
          st[1][hb * 4 + i] = __builtin_amdgcn_mfma_f32_16x16x32_f16(
              kf, qf[1][ks], st[1][hb * 4 + i], 0, 0, 0);
        }
      }
    }
    __builtin_amdgcn_s_setprio(0);
    __syncthreads();  // BAR1: K reads done; V(t) loads drained
    if (t < 15) stageK((t + 1) * 128);  // lands during softmax+PV

    // ---- shift-free softmax, two R12-shape monolithic blocks ----
    unsigned int pu0[16], pu1[16];
    {
      float ps0 = 0.f, ps1 = 0.f;
#pragma unroll
      for (int x = 0; x < 16; ++x) {
        float p0 = fast_exp2(st[0][x >> 1][(x & 1) * 2]);
        float p1 = fast_exp2(st[0][x >> 1][(x & 1) * 2 + 1]);
        ps0 += p0;
        ps1 += p1;
        pu0[x] = pack2_f16(p0, p1);
      }
      ls0 += ps0 + ps1;
    }
    {
      float ps0 = 0.f, ps1 = 0.f;
#pragma unroll
      for (int x = 0; x < 16; ++x) {
        float p0 = fast_exp2(st[1][x >> 1][(x & 1) * 2]);
        float p1 = fast_exp2(st[1][x >> 1][(x & 1) * 2 + 1]);
        ps0 += p0;
        ps1 += p1;
        pu1[x] = pack2_f16(p0, p1);
      }
      ls1 += ps0 + ps1;
    }

    // ---- PV(t): per hb, write both q-sets' P halves then consume ----
    __builtin_amdgcn_s_setprio(1);
#pragma unroll
    for (int hb = 0; hb < 2; ++hb) {
#pragma unroll
      for (int ii = 0; ii < 4; ++ii) {
        union { unsigned int u[2]; uint2 v; } pk;
        pk.u[0] = pu0[hb * 8 + 2 * ii];
        pk.u[1] = pu0[hb * 8 + 2 * ii + 1];
        *(uint2*)(Pw0 + ((32 * ii + 8 * g) ^ psw)) = pk.v;
        pk.u[0] = pu1[hb * 8 + 2 * ii];
        pk.u[1] = pu1[hb * 8 + 2 * ii + 1];
        *(uint2*)(Pw1 + ((32 * ii + 8 * g) ^ psw)) = pk.v;
      }
      const char* Vs = smem + 16384 + hb * 8192;
#pragma unroll
      for (int kb = 0; kb < 2; ++kb) {
        half8 pf0 = *(const half8*)(Pw0 + ((kb * 64 + 16 * g) ^ psw));
        half8 pf1 = *(const half8*)(Pw1 + ((kb * 64 + 16 * g) ^ psw));
        int koff = (kb * 64 + g * 16) ^ swz;
#pragma unroll
        for (int df = 0; df < 4; ++df) {
          half8 vf = *(const half8*)(Vs + (df * 16 + c15) * 128 + koff);
          oacc[0][df] = __builtin_amdgcn_mfma_f32_16x16x32_f16(vf, pf0, oacc[0][df], 0, 0, 0);
          oacc[1][df] = __builtin_amdgcn_mfma_f32_16x16x32_f16(vf, pf1, oacc[1][df], 0, 0, 0);
        }
      }
    }
    __builtin_amdgcn_s_setprio(0);
    __syncthreads();  // BAR2: V reads done; K(t+1) loads drained
    if (t < 15) stageV((t + 1) * 128);  // lands during next QK
  }

  // lsum reduce over g; lsb[qrow] with qrow = w*32 + s*16 + c15
  ls0 += __shfl_xor(ls0, 16, 64);
  ls0 += __shfl_xor(ls0, 32, 64);
  ls1 += __shfl_xor(ls1, 16, 64);
  ls1 += __shfl_xor(ls1, 32, 64);
  if (g == 0) {
    lsb[w * 32 + c15] = ls0;
    lsb[w * 32 + 16 + c15] = ls1;
  }

  // transpose O^T through LDS (overlay; last BAR2 ordered all loop reads)
#pragma unroll
  for (int s = 0; s < 2; ++s)
#pragma unroll
    for (int df = 0; df < 4; ++df)
      *(floatx4*)&Ot[(w * 32 + s * 16 + c15) * 68 + df * 16 + 4 * g] =
          oacc[s][df];
  __syncthreads();

  int b = bh >> 4, h = bh & 15;
  int row = tid >> 1, seg = tid & 1;  // 2 threads/row, 32 floats each
  float inv = 1.f / lsb[row];
  float* dstp = &out[((size_t)b * 2048 + q0 + row) * 1024 + h * 64 + seg * 32];
  const float* srcl = &Ot[row * 68 + seg * 32];
#pragma unroll
  for (int u = 0; u < 8; ++u) {
    floatx4 v = *(const floatx4*)(srcl + u * 4) * inv;
    *(floatx4*)(dstp + u * 4) = v;
  }
}

// ---------------------------------------------------------------------------
extern "C" void kernel_launch(void* const* d_in, const int* in_sizes, int n_in,
                              void* d_out, int out_size, void* d_ws, size_t ws_size,
                              hipStream_t stream) {
  const float* xq = (const float*)d_in[0];
  const float* xk = (const float*)d_in[1];
  const float* wq = (const float*)d_in[2];
  const float* wk = (const float*)d_in[3];
  const float* wv = (const float*)d_in[4];
  char* ws = (char*)d_ws;
  f16* wqt = (f16*)(ws + (0ull << 20));
  f16* wkt = (f16*)(ws + (2ull << 20));
  f16* wvt = (f16*)(ws + (4ull << 20));

  bool fit = ws_size >= (46ull << 20);
  f16 *xqh, *xkh, *qbuf, *kbuf, *vtb;
  if (fit) {
    xqh  = (f16*)(ws + (6ull << 20));
    xkh  = (f16*)(ws + (14ull << 20));
    qbuf = (f16*)(ws + (22ull << 20));
    kbuf = (f16*)(ws + (30ull << 20));
    vtb  = (f16*)(ws + (38ull << 20));
  } else {
    xqh = xkh = nullptr;
    qbuf = (f16*)(ws + (6ull << 20));
    kbuf = (f16*)(ws + (14ull << 20));
    vtb  = (f16*)(ws + (22ull << 20));
  }

  kprep<<<dim3(32, 32, fit ? 5 : 3), 256, 0, stream>>>(xq, xk, wq, wk, wv,
                                                       wqt, wkt, wvt, xqh, xkh);
  if (fit) {
    kproj<1><<<dim3(8, 32, 3), 256, 0, stream>>>(xq, xk, xqh, xkh, wqt, wkt,
                                                 wvt, qbuf, kbuf, vtb);
  } else {
    kproj<0><<<dim3(8, 32, 3), 256, 0, stream>>>(xq, xk, xqh, xkh, wqt, wkt,
                                                 wvt, qbuf, kbuf, vtb);
  }
  kattn<<<512, 256, 0, stream>>>(qbuf, kbuf, vtb, (float*)d_out);
}